// Round 2
// baseline (151.428 us; speedup 1.0000x reference)
//
#include <hip/hip_runtime.h>
#include <stdint.h>

// MemoryEfficientBSpline: out[b,o,p] = sum_i sum_g hat_g(nx[b,i,p]) * coef[b,o,i,g]
// hat_g(nx) = max(0, 1 - |nx - g|),  nx = (clamp(x,-1,1)+1)*2.5 in [0,5], G=6.
// Batched GEMM M=64(o) x N=36864(p) x K=384(i*G) via mfma_f32_16x16x32_f16,
// with B-fragments (hat weights) computed directly in registers (g-major K
// ordering: k = g*16 + i_off within each 16-i chunk).

typedef __fp16 half8_t __attribute__((ext_vector_type(8)));
typedef __fp16 half2_t __attribute__((ext_vector_type(2)));
typedef float f32x4 __attribute__((ext_vector_type(4)));

#define NBATCH 8
#define OD 64
#define ID 64
#define PIX 36864          // 192*192
#define NG 6
#define PT 192             // pixels per block tile
#define KI 16              // i per chunk
#define NCHUNK 4           // 4 * 16 = 64 = ID
#define AROW 104           // A_lds row stride in f16 (96 used; 208B rows: 16B-aligned, 2-way banks)
#define XROW 18            // nx_lds row stride in f32 (16 used; stride 18 dw -> 2-way banks)
#define PTILES (PIX / PT)  // 192 p-tiles per batch

__global__ __launch_bounds__(256, 2)
void kan_mfma(const float* __restrict__ x, const float* __restrict__ coef,
              float* __restrict__ out) {
  const int t = threadIdx.x;
  const int lane = t & 63;
  const int wave = t >> 6;      // 0..3, owns p sub-range [wave*48, wave*48+48)
  const int q8 = lane >> 4;     // 0..3
  const int col = lane & 15;

  const int bid = blockIdx.x;
  const int b = bid / PTILES;   // same-b blocks contiguous -> coef L2 locality
  const int ptile = bid % PTILES;
  const int p0 = ptile * PT;

  __shared__ __fp16 A_lds[OD][AROW] __attribute__((aligned(16)));
  __shared__ float nx_lds[PT][XROW] __attribute__((aligned(16)));

  f32x4 acc[4][3];
#pragma unroll
  for (int i = 0; i < 4; ++i)
#pragma unroll
    for (int j = 0; j < 3; ++j)
      acc[i][j] = (f32x4){0.f, 0.f, 0.f, 0.f};

  const float* xb = x + (size_t)b * ID * PIX + p0;
  const float* cb = coef + (size_t)b * OD * ID * NG;

  const int iof0 = (q8 & 1) * 8;  // which 8 i's this lane's fragment covers
  const int ghalf = q8 >> 1;      // g = 2*ks + ghalf

  for (int c = 0; c < NCHUNK; ++c) {
    const int i0 = c * KI;
    __syncthreads();  // protect LDS from previous chunk's readers

    // ---- stage nx = (clamp(x)+1)*2.5 for 16 i x 192 p (coalesced in p) ----
#pragma unroll
    for (int j = 0; j < (KI * PT) / 256; ++j) {  // 12 iters
      int lin = j * 256 + t;
      int p = lin % PT;
      int iof = lin / PT;
      float xv = xb[(size_t)(i0 + iof) * PIX + p];
      xv = fminf(fmaxf(xv, -1.f), 1.f);
      nx_lds[p][iof] = (xv + 1.f) * 2.5f;
    }

    // ---- stage coef chunk as f16, g-major: A_lds[o][g*16 + i_off] ----
    {
      const int o = t >> 2;
      const int r0 = (t & 3) * 24;
      const float* crow = cb + o * (ID * NG) + i0 * NG + r0;
#pragma unroll
      for (int j = 0; j < 24; ++j) {
        int r = r0 + j;          // r0 % 6 == 0, so these divisions fold to consts
        int iof = r / 6;
        int g = r - iof * 6;
        A_lds[o][g * KI + iof] = (__fp16)crow[j];
      }
    }
    __syncthreads();

    // ---- my 8 nx values per p-subtile (reused across all 3 k-steps) ----
    float nxv[3][8];
#pragma unroll
    for (int pti = 0; pti < 3; ++pti) {
      int p = wave * 48 + pti * 16 + col;
#pragma unroll
      for (int j = 0; j < 8; ++j)
        nxv[pti][j] = nx_lds[p][iof0 + j];
    }

#pragma unroll
    for (int ks = 0; ks < 3; ++ks) {
      half8_t af[4];
#pragma unroll
      for (int ot = 0; ot < 4; ++ot)
        af[ot] = *(const half8_t*)&A_lds[ot * 16 + col][ks * 32 + q8 * 8];

      const float gf = (float)(2 * ks + ghalf);
#pragma unroll
      for (int pti = 0; pti < 3; ++pti) {
        union { half2_t h2[4]; half8_t v; } bu;
#pragma unroll
        for (int jj = 0; jj < 4; ++jj) {
          float h0 = fmaxf(0.f, 1.f - fabsf(nxv[pti][2 * jj] - gf));
          float h1 = fmaxf(0.f, 1.f - fabsf(nxv[pti][2 * jj + 1] - gf));
          bu.h2[jj] = __builtin_amdgcn_cvt_pkrtz(h0, h1);
        }
#pragma unroll
        for (int ot = 0; ot < 4; ++ot)
          acc[ot][pti] = __builtin_amdgcn_mfma_f32_16x16x32_f16(
              af[ot], bu.v, acc[ot][pti], 0, 0, 0);
      }
    }
  }

  // ---- epilogue: C row = q8*4 + reg, col = lane&15 ----
  float* ob = out + (size_t)b * OD * PIX + p0;
#pragma unroll
  for (int ot = 0; ot < 4; ++ot) {
#pragma unroll
    for (int pti = 0; pti < 3; ++pti) {
      int p = wave * 48 + pti * 16 + col;
#pragma unroll
      for (int r = 0; r < 4; ++r) {
        int o = ot * 16 + q8 * 4 + r;
        ob[(size_t)o * PIX + p] = acc[ot][pti][r];
      }
    }
  }
}

extern "C" void kernel_launch(void* const* d_in, const int* in_sizes, int n_in,
                              void* d_out, int out_size, void* d_ws, size_t ws_size,
                              hipStream_t stream) {
  const float* x = (const float*)d_in[0];
  const float* coef = (const float*)d_in[1];
  float* out = (float*)d_out;
  dim3 grid(NBATCH * PTILES);
  dim3 block(256);
  hipLaunchKernelGGL(kan_mfma, grid, block, 0, stream, x, coef, out);
}